// Round 14
// baseline (66.334 us; speedup 1.0000x reference)
//
#include <hip/hip_runtime.h>
#include <hip/hip_fp16.h>
#include <hip/hip_bf16.h>
#include <math.h>

// Problem constants (from reference)
#define B_SZ 8192
#define L_SZ 50
#define D_SZ 128
#define C_SZ 256        // output cols of W_cpr
#define K_SZ 256        // = 2*D, GEMM K
#define R_SZ 7
#define V_SZ 100000

typedef __attribute__((ext_vector_type(8))) short bf16x8;
typedef __attribute__((ext_vector_type(4))) float f32x4;

#define EMB_N4 (V_SZ * D_SZ / 4)     // 3,200,000 float4s of emb
#define W_N4   (C_SZ * K_SZ / 4)     // 16,384 float4s of W_cpr

// ---------------------------------------------------------------------------
// Kernel A: fused dtype prep. First EMB_N4 threads convert emb f32->fp16;
// next W_N4 convert W_cpr f32->bf16 (row-major [n][k], MFMA B-ready).
// HBM-roofline bound (77 MB @ ~6.5 TB/s ~ 12 us).
// ---------------------------------------------------------------------------
__global__ __launch_bounds__(256) void k_conv(const float* __restrict__ emb,
                                              __half* __restrict__ E16,
                                              const float* __restrict__ W,
                                              __hip_bfloat16* __restrict__ W16) {
    int i = blockIdx.x * 256 + threadIdx.x;
    if (i < EMB_N4) {
        float4 v = ((const float4*)emb)[i];
        union { __half2 h[2]; uint2 u; } pk;
        pk.h[0].x = __float2half_rn(v.x); pk.h[0].y = __float2half_rn(v.y);
        pk.h[1].x = __float2half_rn(v.z); pk.h[1].y = __float2half_rn(v.w);
        ((uint2*)E16)[i] = pk.u;
    } else if (i < EMB_N4 + W_N4) {
        const int j = i - EMB_N4;
        float4 v = ((const float4*)W)[j];
        union { __hip_bfloat16 b[4]; float2 f; } pk;
        pk.b[0] = __float2bfloat16(v.x); pk.b[1] = __float2bfloat16(v.y);
        pk.b[2] = __float2bfloat16(v.z); pk.b[3] = __float2bfloat16(v.w);
        ((float2*)W16)[j] = pk.f;
    }
}

// ---------------------------------------------------------------------------
// Gather kernel (fp16 table): 1 batch row per WAVE, 4 waves/block, grid 2048
// (32 waves/CU residency). Per iteration: SIX independent unconditional 1 KB
// row-loads in one basic block (12 tokens/side) -> 6 KB in flight/wave,
// nit = ceil(max/12) (typ. 3 vs R13's 4). VGPR kept <=64 (8 waves/SIMD).
// Output X in bf16 (MFMA A-ready).
// ---------------------------------------------------------------------------
__global__ __launch_bounds__(256, 8) void k_gather_h(
    const int* __restrict__ ltok, const int* __restrict__ rtok,
    const int* __restrict__ lmask, const int* __restrict__ rmask,
    const __half* __restrict__ E16, __hip_bfloat16* __restrict__ X16) {

    __shared__ int ctok[4][2][52];

    const int wave = threadIdx.x >> 6;
    const int lane = threadIdx.x & 63;
    const int grp = lane >> 4;   // 16-lane group 0..3 (token slot)
    const int sub = lane & 15;   // float4 slot within a 256 B fp16 row
    const int row = blockIdx.x * 4 + wave;

    int lt = 0, rt = 0, lm = 0, rm = 0;
    if (lane < L_SZ) {
        const size_t o = (size_t)row * L_SZ + lane;
        lt = ltok[o]; lm = lmask[o]; rt = rtok[o]; rm = rmask[o];
    }
    const unsigned long long ltm = (1ULL << lane) - 1;
    const unsigned long long balL = __ballot(lm != 0);
    const unsigned long long balR = __ballot(rm != 0);
    const int cntL = __popcll(balL);
    const int cntR = __popcll(balR);
    if (lm) ctok[wave][0][__popcll(balL & ltm)] = lt;
    if (rm) ctok[wave][1][__popcll(balR & ltm)] = rt;
    if (lane == 0) {
        if (cntL == 0) ctok[wave][0][0] = 0;
        if (cntR == 0) ctok[wave][1][0] = 0;
    }

    const float4* E = (const float4*)E16;  // [V][16] float4 (8 halves each)
    float aL[8] = {0}, aR[8] = {0};
    const int maxc = max(cntL, cntR);
    const int nit = (maxc + 11) / 12;      // 12 tokens/side per iteration

    for (int it = 0; it < nit; ++it) {
        float4 eL[3], eR[3];
        float sL[3], sR[3];
#pragma unroll
        for (int q = 0; q < 3; ++q) {
            const int idx = it * 12 + q * 4 + grp;
            int iL = min(idx, cntL - 1); iL = (iL < 0) ? 0 : iL;
            int iR = min(idx, cntR - 1); iR = (iR < 0) ? 0 : iR;
            const int tL = ctok[wave][0][iL];
            const int tR = ctok[wave][1][iR];
            eL[q] = E[((size_t)tL << 4) + sub];
            eR[q] = E[((size_t)tR << 4) + sub];
            sL[q] = (idx < cntL) ? 1.f : 0.f;
            sR[q] = (idx < cntR) ? 1.f : 0.f;
        }
#define ACC8(A, ev, sc)                                                   \
        {                                                                 \
            const __half2* hp = (const __half2*)&ev;                      \
            _Pragma("unroll")                                             \
            for (int q2 = 0; q2 < 4; ++q2) {                              \
                A[2 * q2]     = fmaf(sc, __half2float(hp[q2].x), A[2 * q2]);     \
                A[2 * q2 + 1] = fmaf(sc, __half2float(hp[q2].y), A[2 * q2 + 1]); \
            }                                                             \
        }
#pragma unroll
        for (int q = 0; q < 3; ++q) {
            ACC8(aL, eL[q], sL[q])
            ACC8(aR, eR[q], sR[q])
        }
#undef ACC8
    }

#pragma unroll
    for (int j = 0; j < 8; ++j) {
        aL[j] += __shfl_xor(aL[j], 16);
        aL[j] += __shfl_xor(aL[j], 32);
        aR[j] += __shfl_xor(aR[j], 16);
        aR[j] += __shfl_xor(aR[j], 32);
    }

    // store as bf16: lane (grp, sub) owns dims [sub*8 .. sub*8+7] of its side
    union { __hip_bfloat16 b[8]; float4 v; } pk;
    if (grp == 0) {
#pragma unroll
        for (int j = 0; j < 8; ++j) pk.b[j] = __float2bfloat16(aL[j]);
        *(float4*)((char*)X16 + (size_t)row * 512 + sub * 16) = pk.v;
    } else if (grp == 1) {
#pragma unroll
        for (int j = 0; j < 8; ++j) pk.b[j] = __float2bfloat16(aR[j]);
        *(float4*)((char*)X16 + (size_t)row * 512 + 256 + sub * 16) = pk.v;
    }
}

// ---------------------------------------------------------------------------
// MLP kernel v6 (MFMA, L2-resident W, no LDS staging):
// h = LeakyReLU(X@W^T + b); logits = h@W_sm^T + b_sm; out = log_softmax.
// grid 512 (16 rows/block), 256 thr = 4 waves; wave w owns the 64-col
// quarter: 4 ntiles x 8 ksteps of mfma_f32_16x16x32_bf16 with B-fragments
// loaded straight from L2-resident W16 (128 KB, shared by all blocks) and
// A-fragments from X16. LDS only for h (17 KB) -> no occupancy cap, no
// staging barrier. Layouts (m89-verified): A/B row|col=lane&15,
// k=(lane>>4)*8+j ; C/D col=lane&15, row=(lane>>4)*4+reg.
// ---------------------------------------------------------------------------
__global__ __launch_bounds__(256) void k_mlp_mfma(
    const __hip_bfloat16* __restrict__ X16,
    const __hip_bfloat16* __restrict__ W16,
    const float* __restrict__ b_cpr, const float* __restrict__ W_sm,
    const float* __restrict__ b_sm, float* __restrict__ out) {

    __shared__ float h_lds[16][C_SZ + 4];    // 16.6 KB
    __shared__ float l_lds[16][R_SZ];

    const int tid = threadIdx.x;
    const int wave = tid >> 6;
    const int lane = tid & 63;
    const int row0 = blockIdx.x * 16;
    const int w_c = wave * 64;           // wave's col quarter

    // ---- A-frag loads: 8 ksteps (all waves read the same A; L2-hit) ----
    bf16x8 av[8];
    {
        const int arow = row0 + (lane & 15);
        const int kbase = (lane >> 4) * 8;
#pragma unroll
        for (int ks = 0; ks < 8; ++ks)
            av[ks] = *(const bf16x8*)(X16 + (size_t)arow * K_SZ + ks * 32 + kbase);
    }

    // ---- MFMA: 8 ksteps x 4 ntiles; B-frags from global (L2) ----
    f32x4 acc[4];
#pragma unroll
    for (int nt = 0; nt < 4; ++nt) acc[nt] = (f32x4){0.f, 0.f, 0.f, 0.f};

    const int bl_n = lane & 15;
    const int bl_k = (lane >> 4) * 8;
#pragma unroll
    for (int ks = 0; ks < 8; ++ks) {
        bf16x8 bv[4];
#pragma unroll
        for (int nt = 0; nt < 4; ++nt)
            bv[nt] = *(const bf16x8*)(W16 +
                (size_t)(w_c + nt * 16 + bl_n) * K_SZ + ks * 32 + bl_k);
#pragma unroll
        for (int nt = 0; nt < 4; ++nt)
            acc[nt] = __builtin_amdgcn_mfma_f32_16x16x32_bf16(
                av[ks], bv[nt], acc[nt], 0, 0, 0);
    }

    // ---- bias + LeakyReLU -> h ----
    {
        const int hr = (lane >> 4) * 4;          // + j
        const int hcb = w_c + bl_n;              // + nt*16
#pragma unroll
        for (int nt = 0; nt < 4; ++nt) {
            const int col = hcb + nt * 16;
            const float b = b_cpr[col];
#pragma unroll
            for (int j = 0; j < 4; ++j) {
                float h = acc[nt][j] + b;
                h_lds[hr + j][col] = (h >= 0.f) ? h : 0.01f * h;
            }
        }
    }
    __syncthreads();

    // ---- head: 112 threads, one (row, r) dot of length 256 ----
    if (tid < 16 * R_SZ) {
        const int bl = tid / R_SZ;
        const int rh = tid % R_SZ;
        const float* wr = W_sm + rh * C_SZ;
        float s = b_sm[rh];
#pragma unroll 4
        for (int c = 0; c < C_SZ; c += 4) {
            float4 hv = *(const float4*)&h_lds[bl][c];
            s = fmaf(hv.x, wr[c + 0], s);
            s = fmaf(hv.y, wr[c + 1], s);
            s = fmaf(hv.z, wr[c + 2], s);
            s = fmaf(hv.w, wr[c + 3], s);
        }
        l_lds[bl][rh] = s;
    }
    __syncthreads();

    // ---- log-softmax over R=7 ----
    if (tid < 16) {
        float m = -INFINITY;
#pragma unroll
        for (int rh = 0; rh < R_SZ; ++rh) m = fmaxf(m, l_lds[tid][rh]);
        float se = 0.f;
#pragma unroll
        for (int rh = 0; rh < R_SZ; ++rh) se += expf(l_lds[tid][rh] - m);
        const float lse = m + logf(se);
        const size_t ob = (size_t)(row0 + tid) * R_SZ;
#pragma unroll
        for (int rh = 0; rh < R_SZ; ++rh) out[ob + rh] = l_lds[tid][rh] - lse;
    }
}

// ---------------------------------------------------------------------------
extern "C" void kernel_launch(void* const* d_in, const int* in_sizes, int n_in,
                              void* d_out, int out_size, void* d_ws, size_t ws_size,
                              hipStream_t stream) {
    const int* ltok = (const int*)d_in[0];
    const int* rtok = (const int*)d_in[1];
    const int* lmask = (const int*)d_in[2];
    const int* rmask = (const int*)d_in[3];
    const float* emb = (const float*)d_in[4];
    const float* W_cpr = (const float*)d_in[5];
    const float* b_cpr = (const float*)d_in[6];
    const float* W_sm = (const float*)d_in[7];
    const float* b_sm = (const float*)d_in[8];
    float* out = (float*)d_out;

    // ws layout: E16 [V][128] fp16 (25.6 MB) | W16 [256][256] bf16 (128 KB)
    //            | X16 [B][256] bf16 (4 MB)
    const size_t E16_BYTES = (size_t)V_SZ * D_SZ * sizeof(__half);
    const size_t W16_BYTES = (size_t)C_SZ * K_SZ * sizeof(__hip_bfloat16);
    __half* E16 = (__half*)d_ws;
    __hip_bfloat16* W16 = (__hip_bfloat16*)((char*)d_ws + E16_BYTES);
    __hip_bfloat16* X16 =
        (__hip_bfloat16*)((char*)d_ws + E16_BYTES + W16_BYTES);

    const int nconv = EMB_N4 + W_N4;
    k_conv<<<(nconv + 255) / 256, 256, 0, stream>>>(emb, E16, W_cpr, W16);
    k_gather_h<<<B_SZ / 4, 256, 0, stream>>>(ltok, rtok, lmask, rmask,
                                             E16, X16);
    k_mlp_mfma<<<B_SZ / 16, 256, 0, stream>>>(X16, W16, b_cpr, W_sm,
                                              b_sm, out);
}

// Round 15
// 46.935 us; speedup vs baseline: 1.4133x; 1.4133x over previous
//
#include <hip/hip_runtime.h>
#include <hip/hip_fp16.h>
#include <hip/hip_bf16.h>
#include <math.h>

// Problem constants (from reference)
#define B_SZ 8192
#define L_SZ 50
#define D_SZ 128
#define C_SZ 256        // output cols of W_cpr
#define K_SZ 256        // = 2*D, GEMM K
#define R_SZ 7
#define V_SZ 100000

typedef __attribute__((ext_vector_type(8))) short bf16x8;
typedef __attribute__((ext_vector_type(4))) float f32x4;

#define EMB_N4 (V_SZ * D_SZ / 4)     // 3,200,000 float4s of emb
#define W_N4   (C_SZ * K_SZ / 4)     // 16,384 float4s of W_cpr

// ---------------------------------------------------------------------------
// Kernel A: fused dtype prep. First EMB_N4 threads convert emb f32->fp16;
// next W_N4 convert W_cpr f32->bf16 (row-major [n][k], MFMA B-ready).
// HBM-roofline bound (77 MB @ ~6.5 TB/s ~ 12 us).
// ---------------------------------------------------------------------------
__global__ __launch_bounds__(256) void k_conv(const float* __restrict__ emb,
                                              __half* __restrict__ E16,
                                              const float* __restrict__ W,
                                              __hip_bfloat16* __restrict__ W16) {
    int i = blockIdx.x * 256 + threadIdx.x;
    if (i < EMB_N4) {
        float4 v = ((const float4*)emb)[i];
        union { __half2 h[2]; uint2 u; } pk;
        pk.h[0].x = __float2half_rn(v.x); pk.h[0].y = __float2half_rn(v.y);
        pk.h[1].x = __float2half_rn(v.z); pk.h[1].y = __float2half_rn(v.w);
        ((uint2*)E16)[i] = pk.u;
    } else if (i < EMB_N4 + W_N4) {
        const int j = i - EMB_N4;
        float4 v = ((const float4*)W)[j];
        union { __hip_bfloat16 b[4]; float2 f; } pk;
        pk.b[0] = __float2bfloat16(v.x); pk.b[1] = __float2bfloat16(v.y);
        pk.b[2] = __float2bfloat16(v.z); pk.b[3] = __float2bfloat16(v.w);
        ((float2*)W16)[j] = pk.f;
    }
}

// ---------------------------------------------------------------------------
// Gather kernel (fp16 table): 1 batch row per WAVE, 4 waves/block, grid 2048
// (32 waves/CU residency). Per iteration: FOUR independent unconditional
// 1 KB row-loads in one basic block (8 tokens/side) -> 4 KB in flight/wave,
// VGPR <= 64 (8 waves/SIMD). Compacted token lists in LDS; pad slots re-read
// a clamped index with scale 0 (L1 hits). Output X in bf16 (MFMA A-ready).
// [R13-proven config; R14's 6-load variant exceeded the 64-VGPR cap.]
// ---------------------------------------------------------------------------
__global__ __launch_bounds__(256, 8) void k_gather_h(
    const int* __restrict__ ltok, const int* __restrict__ rtok,
    const int* __restrict__ lmask, const int* __restrict__ rmask,
    const __half* __restrict__ E16, __hip_bfloat16* __restrict__ X16) {

    __shared__ int ctok[4][2][52];

    const int wave = threadIdx.x >> 6;
    const int lane = threadIdx.x & 63;
    const int grp = lane >> 4;   // 16-lane group 0..3 (token slot)
    const int sub = lane & 15;   // float4 slot within a 256 B fp16 row
    const int row = blockIdx.x * 4 + wave;

    int lt = 0, rt = 0, lm = 0, rm = 0;
    if (lane < L_SZ) {
        const size_t o = (size_t)row * L_SZ + lane;
        lt = ltok[o]; lm = lmask[o]; rt = rtok[o]; rm = rmask[o];
    }
    const unsigned long long ltm = (1ULL << lane) - 1;
    const unsigned long long balL = __ballot(lm != 0);
    const unsigned long long balR = __ballot(rm != 0);
    const int cntL = __popcll(balL);
    const int cntR = __popcll(balR);
    if (lm) ctok[wave][0][__popcll(balL & ltm)] = lt;
    if (rm) ctok[wave][1][__popcll(balR & ltm)] = rt;
    if (lane == 0) {
        if (cntL == 0) ctok[wave][0][0] = 0;
        if (cntR == 0) ctok[wave][1][0] = 0;
    }

    const float4* E = (const float4*)E16;  // [V][16] float4 (8 halves each)
    float aL[8] = {0}, aR[8] = {0};
    const int maxc = max(cntL, cntR);
    const int nit = (maxc + 7) >> 3;       // 8 tokens/side per iteration

    for (int it = 0; it < nit; ++it) {
        const int idxA = it * 8 + grp;
        const int idxB = it * 8 + 4 + grp;
        // --- issue all four 1 KB loads first (independent, one BB) ---
        int iiA0 = min(idxA, cntL - 1); iiA0 = (iiA0 < 0) ? 0 : iiA0;
        int iiB0 = min(idxB, cntL - 1); iiB0 = (iiB0 < 0) ? 0 : iiB0;
        int iiA1 = min(idxA, cntR - 1); iiA1 = (iiA1 < 0) ? 0 : iiA1;
        int iiB1 = min(idxB, cntR - 1); iiB1 = (iiB1 < 0) ? 0 : iiB1;
        const int tA0 = ctok[wave][0][iiA0];
        const int tB0 = ctok[wave][0][iiB0];
        const int tA1 = ctok[wave][1][iiA1];
        const int tB1 = ctok[wave][1][iiB1];
        const float4 eA0 = E[((size_t)tA0 << 4) + sub];
        const float4 eB0 = E[((size_t)tB0 << 4) + sub];
        const float4 eA1 = E[((size_t)tA1 << 4) + sub];
        const float4 eB1 = E[((size_t)tB1 << 4) + sub];
        const float sA0 = (idxA < cntL) ? 1.f : 0.f;
        const float sB0 = (idxB < cntL) ? 1.f : 0.f;
        const float sA1 = (idxA < cntR) ? 1.f : 0.f;
        const float sB1 = (idxB < cntR) ? 1.f : 0.f;
        // --- accumulate ---
#define ACC8(A, ev, sc)                                                   \
        {                                                                 \
            const __half2* hp = (const __half2*)&ev;                      \
            _Pragma("unroll")                                             \
            for (int q = 0; q < 4; ++q) {                                 \
                A[2 * q]     = fmaf(sc, __half2float(hp[q].x), A[2 * q]);       \
                A[2 * q + 1] = fmaf(sc, __half2float(hp[q].y), A[2 * q + 1]);   \
            }                                                             \
        }
        ACC8(aL, eA0, sA0)
        ACC8(aL, eB0, sB0)
        ACC8(aR, eA1, sA1)
        ACC8(aR, eB1, sB1)
#undef ACC8
    }

#pragma unroll
    for (int j = 0; j < 8; ++j) {
        aL[j] += __shfl_xor(aL[j], 16);
        aL[j] += __shfl_xor(aL[j], 32);
        aR[j] += __shfl_xor(aR[j], 16);
        aR[j] += __shfl_xor(aR[j], 32);
    }

    // store as bf16: lane (grp, sub) owns dims [sub*8 .. sub*8+7] of its side
    union { __hip_bfloat16 b[8]; float4 v; } pk;
    if (grp == 0) {
#pragma unroll
        for (int j = 0; j < 8; ++j) pk.b[j] = __float2bfloat16(aL[j]);
        *(float4*)((char*)X16 + (size_t)row * 512 + sub * 16) = pk.v;
    } else if (grp == 1) {
#pragma unroll
        for (int j = 0; j < 8; ++j) pk.b[j] = __float2bfloat16(aR[j]);
        *(float4*)((char*)X16 + (size_t)row * 512 + 256 + sub * 16) = pk.v;
    }
}

// ---------------------------------------------------------------------------
// MLP kernel v5 (MFMA, 512 thr): h = LeakyReLU(X@W^T + b);
// logits = h@W_sm^T + b_sm; out = log_softmax.
// 8 waves; wave (w>>2) takes 16-row half, (w&3) takes 64-col quarter:
// 4 ntiles x 8 ksteps = 32 mfma_f32_16x16x32_bf16 per wave. Whole W16 in
// LDS [256][264] bf16 (135 KB, +8 pad, coalesced stage). A-frags prefetched
// from global X16. h (f32) aliased onto the W LDS region for the head.
// [R13-proven config; R14's L2-direct B-reads were 16-segment uncoalesced.]
// Layouts (m89-verified): A/B: row|col=lane&15, k=(lane>>4)*8+j ;
// C/D: col=lane&15, row=(lane>>4)*4+reg.
// ---------------------------------------------------------------------------
__global__ __launch_bounds__(512) void k_mlp_mfma(
    const __hip_bfloat16* __restrict__ X16,
    const __hip_bfloat16* __restrict__ W16,
    const float* __restrict__ b_cpr, const float* __restrict__ W_sm,
    const float* __restrict__ b_sm, float* __restrict__ out) {

    __shared__ unsigned short Wl[256][264];   // 135168 B (bf16 bits)
    __shared__ float l_lds[32][R_SZ];

    const int tid = threadIdx.x;
    const int wave = tid >> 6;
    const int lane = tid & 63;
    const int row0 = blockIdx.x * 32;
    const int w_r = (wave >> 2) * 16;    // wave's row offset (0 or 16)
    const int w_c = (wave & 3) * 64;     // wave's col offset (0/64/128/192)

    // ---- A-frag prefetch: 8 ksteps, lane reads X16[row][k0..k0+7] ----
    bf16x8 av[8];
    {
        const int arow = row0 + w_r + (lane & 15);
        const int kbase = (lane >> 4) * 8;
#pragma unroll
        for (int ks = 0; ks < 8; ++ks)
            av[ks] = *(const bf16x8*)(X16 + (size_t)arow * K_SZ + ks * 32 + kbase);
    }

    // ---- stage whole W16 into LDS: 8192 16B-chunks, 16 per thread ----
    {
#pragma unroll
        for (int i = 0; i < 16; ++i) {
            const int flat = i * 512 + tid;
            const int n = flat >> 5;
            const int c = flat & 31;
            *(float4*)&Wl[n][c * 8] =
                *(const float4*)(W16 + (size_t)n * K_SZ + c * 8);
        }
    }
    __syncthreads();

    // ---- MFMA: 8 ksteps x 4 ntiles per wave ----
    f32x4 acc[4];
#pragma unroll
    for (int nt = 0; nt < 4; ++nt) acc[nt] = (f32x4){0.f, 0.f, 0.f, 0.f};

    const int bl_n = lane & 15;
    const int bl_k = (lane >> 4) * 8;
#pragma unroll
    for (int ks = 0; ks < 8; ++ks) {
#pragma unroll
        for (int nt = 0; nt < 4; ++nt) {
            const bf16x8 bv =
                *(const bf16x8*)&Wl[w_c + nt * 16 + bl_n][ks * 32 + bl_k];
            acc[nt] = __builtin_amdgcn_mfma_f32_16x16x32_bf16(
                av[ks], bv, acc[nt], 0, 0, 0);
        }
    }
    __syncthreads();   // all B-frag reads done before h aliases Wl

    // ---- bias + LeakyReLU -> h (f32, aliased onto Wl region) ----
    float (*h_lds)[C_SZ + 4] = (float (*)[C_SZ + 4])&Wl[0][0];
    {
        const int hr = w_r + (lane >> 4) * 4;    // + j
        const int hcb = w_c + bl_n;              // + nt*16
#pragma unroll
        for (int nt = 0; nt < 4; ++nt) {
            const int col = hcb + nt * 16;
            const float b = b_cpr[col];
#pragma unroll
            for (int j = 0; j < 4; ++j) {
                float h = acc[nt][j] + b;
                h_lds[hr + j][col] = (h >= 0.f) ? h : 0.01f * h;
            }
        }
    }
    __syncthreads();

    // ---- head: 224 threads, one (row, r) dot of length 256 ----
    if (tid < 32 * R_SZ) {
        const int bl = tid / R_SZ;
        const int rh = tid % R_SZ;
        const float* wr = W_sm + rh * C_SZ;
        float s = b_sm[rh];
#pragma unroll 4
        for (int c = 0; c < C_SZ; c += 4) {
            float4 hv = *(const float4*)&h_lds[bl][c];
            s = fmaf(hv.x, wr[c + 0], s);
            s = fmaf(hv.y, wr[c + 1], s);
            s = fmaf(hv.z, wr[c + 2], s);
            s = fmaf(hv.w, wr[c + 3], s);
        }
        l_lds[bl][rh] = s;
    }
    __syncthreads();

    // ---- log-softmax over R=7 ----
    if (tid < 32) {
        float m = -INFINITY;
#pragma unroll
        for (int rh = 0; rh < R_SZ; ++rh) m = fmaxf(m, l_lds[tid][rh]);
        float se = 0.f;
#pragma unroll
        for (int rh = 0; rh < R_SZ; ++rh) se += expf(l_lds[tid][rh] - m);
        const float lse = m + logf(se);
        const size_t ob = (size_t)(row0 + tid) * R_SZ;
#pragma unroll
        for (int rh = 0; rh < R_SZ; ++rh) out[ob + rh] = l_lds[tid][rh] - lse;
    }
}

// ---------------------------------------------------------------------------
extern "C" void kernel_launch(void* const* d_in, const int* in_sizes, int n_in,
                              void* d_out, int out_size, void* d_ws, size_t ws_size,
                              hipStream_t stream) {
    const int* ltok = (const int*)d_in[0];
    const int* rtok = (const int*)d_in[1];
    const int* lmask = (const int*)d_in[2];
    const int* rmask = (const int*)d_in[3];
    const float* emb = (const float*)d_in[4];
    const float* W_cpr = (const float*)d_in[5];
    const float* b_cpr = (const float*)d_in[6];
    const float* W_sm = (const float*)d_in[7];
    const float* b_sm = (const float*)d_in[8];
    float* out = (float*)d_out;

    // ws layout: E16 [V][128] fp16 (25.6 MB) | W16 [256][256] bf16 (128 KB)
    //            | X16 [B][256] bf16 (4 MB)
    const size_t E16_BYTES = (size_t)V_SZ * D_SZ * sizeof(__half);
    const size_t W16_BYTES = (size_t)C_SZ * K_SZ * sizeof(__hip_bfloat16);
    __half* E16 = (__half*)d_ws;
    __hip_bfloat16* W16 = (__hip_bfloat16*)((char*)d_ws + E16_BYTES);
    __hip_bfloat16* X16 =
        (__hip_bfloat16*)((char*)d_ws + E16_BYTES + W16_BYTES);

    const int nconv = EMB_N4 + W_N4;
    k_conv<<<(nconv + 255) / 256, 256, 0, stream>>>(emb, E16, W_cpr, W16);
    k_gather_h<<<B_SZ / 4, 256, 0, stream>>>(ltok, rtok, lmask, rmask,
                                             E16, X16);
    k_mlp_mfma<<<B_SZ / 32, 512, 0, stream>>>(X16, W16, b_cpr, W_sm,
                                              b_sm, out);
}